// Round 1
// baseline (868.158 us; speedup 1.0000x reference)
//
#include <hip/hip_runtime.h>

typedef unsigned short ushort;
typedef float f32x4 __attribute__((ext_vector_type(4)));
typedef __bf16 bf16x8 __attribute__((ext_vector_type(8)));

#define N_TOK 131072
#define C_DIM 256
#define H_HEADS 8
#define K_WIN 128
#define NB (N_TOK / K_WIN)
#define ATTN_SCALE 0.17677669529663687f
#define LN_EPS 1e-5f

__device__ __forceinline__ ushort f2b(float f) {
  unsigned u = __float_as_uint(f);
  unsigned r = (u + 0x7fffu + ((u >> 16) & 1u)) >> 16;
  return (ushort)r;
}

// async global->LDS 16B copy. LDS dest is wave-uniform base; HW adds lane*16.
__device__ __forceinline__ void cp16(const void* gptr, void* lptr) {
  __builtin_amdgcn_global_load_lds(
      (const __attribute__((address_space(1))) unsigned int*)(unsigned long long)gptr,
      (__attribute__((address_space(3))) unsigned int*)(unsigned)(unsigned long long)lptr,
      16, 0, 0);
}

__global__ void f2b_kernel(const float* __restrict__ in, ushort* __restrict__ out, int n) {
  int i = blockIdx.x * 256 + threadIdx.x;
  if (i < n) out[i] = f2b(in[i]);
}

// LayerNorm over 256 cols, one wave per row, fp32 in -> bf16 out
__global__ __launch_bounds__(256) void ln_kernel(const float* __restrict__ x,
                                                 const float* __restrict__ g,
                                                 const float* __restrict__ b,
                                                 ushort* __restrict__ out) {
  int row = blockIdx.x * 4 + (threadIdx.x >> 6);
  int lane = threadIdx.x & 63;
  const float4* px = reinterpret_cast<const float4*>(x + (size_t)row * C_DIM);
  float4 v = px[lane];
  float s = v.x + v.y + v.z + v.w;
#pragma unroll
  for (int off = 32; off; off >>= 1) s += __shfl_xor(s, off);
  float mu = s * (1.0f / C_DIM);
  float dx = v.x - mu, dy = v.y - mu, dz = v.z - mu, dw = v.w - mu;
  float q = dx * dx + dy * dy + dz * dz + dw * dw;
#pragma unroll
  for (int off = 32; off; off >>= 1) q += __shfl_xor(q, off);
  float rstd = rsqrtf(q * (1.0f / C_DIM) + LN_EPS);
  float4 gv = reinterpret_cast<const float4*>(g)[lane];
  float4 bv = reinterpret_cast<const float4*>(b)[lane];
  ushort4 o;
  o.x = f2b(dx * rstd * gv.x + bv.x);
  o.y = f2b(dy * rstd * gv.y + bv.y);
  o.z = f2b(dz * rstd * gv.z + bv.z);
  o.w = f2b(dw * rstd * gv.w + bv.w);
  reinterpret_cast<ushort4*>(out + (size_t)row * C_DIM)[lane] = o;
}

// C = A(MxK) @ B(NxK)^T, bf16 in, 128x128 tile, BK=32, 4 waves, 4x4 frags/wave.
// EPI 0: bf16 out, row scatter via scatter[] (+bias)      [QKV]
// EPI 1: f32 out = acc + bias + resid                      [proj / mlp2]
// EPI 2: bf16 out = gelu_exact(acc + bias)                 [mlp1]
template <int EPI>
__global__ __launch_bounds__(256, 2) void gemm_bt(
    const ushort* __restrict__ A, const ushort* __restrict__ B,
    const float* __restrict__ bias, void* __restrict__ out,
    const int* __restrict__ scatter, const float* __restrict__ resid,
    int M, int Nn, int Kk) {
  __shared__ ushort sA[128 * 32];
  __shared__ ushort sB[128 * 32];
  const int tid = threadIdx.x;
  const int wave = tid >> 6;
  const int lane = tid & 63;
  const int quad = lane >> 4;
  const int l16 = lane & 15;
  const int ntn = Nn >> 7;
  const int mt = blockIdx.x / ntn;
  const int nt = blockIdx.x % ntn;
  const int m0 = mt << 7, n0 = nt << 7;
  const int rw = (wave >> 1) << 6;
  const int cw = (wave & 1) << 6;
  const int c0 = tid, c1 = tid + 256;

  f32x4 acc[4][4] = {};

  for (int k0 = 0; k0 < Kk; k0 += 32) {
    __syncthreads();  // protect LDS from overwrite while prior reads in flight
    cp16(A + ((size_t)(m0 + (c0 >> 2)) * Kk + k0 + (c0 & 3) * 8), sA + wave * 512);
    cp16(A + ((size_t)(m0 + (c1 >> 2)) * Kk + k0 + (c1 & 3) * 8), sA + 2048 + wave * 512);
    cp16(B + ((size_t)(n0 + (c0 >> 2)) * Kk + k0 + (c0 & 3) * 8), sB + wave * 512);
    cp16(B + ((size_t)(n0 + (c1 >> 2)) * Kk + k0 + (c1 & 3) * 8), sB + 2048 + wave * 512);
    __syncthreads();  // drains vmcnt: staging complete

    bf16x8 af[4], bfr[4];
#pragma unroll
    for (int i = 0; i < 4; i++)
      af[i] = *(const bf16x8*)(sA + (rw + i * 16 + l16) * 32 + quad * 8);
#pragma unroll
    for (int i = 0; i < 4; i++)
      bfr[i] = *(const bf16x8*)(sB + (cw + i * 16 + l16) * 32 + quad * 8);
#pragma unroll
    for (int mi = 0; mi < 4; mi++)
#pragma unroll
      for (int ni = 0; ni < 4; ni++)
        acc[mi][ni] = __builtin_amdgcn_mfma_f32_16x16x32_bf16(af[mi], bfr[ni], acc[mi][ni], 0, 0, 0);
  }

  float bv[4];
#pragma unroll
  for (int ni = 0; ni < 4; ni++) bv[ni] = bias[n0 + cw + ni * 16 + l16];

#pragma unroll
  for (int mi = 0; mi < 4; mi++) {
#pragma unroll
    for (int r = 0; r < 4; r++) {
      int row = m0 + rw + mi * 16 + quad * 4 + r;
      if (EPI == 0) {
        int orow = scatter[row];
        ushort* po = (ushort*)out + (size_t)orow * Nn + n0 + cw + l16;
#pragma unroll
        for (int ni = 0; ni < 4; ni++) po[ni * 16] = f2b(acc[mi][ni][r] + bv[ni]);
      } else if (EPI == 1) {
        size_t base = (size_t)row * Nn + n0 + cw + l16;
        float* po = (float*)out;
#pragma unroll
        for (int ni = 0; ni < 4; ni++)
          po[base + ni * 16] = acc[mi][ni][r] + bv[ni] + resid[base + ni * 16];
      } else {
        ushort* po = (ushort*)out + (size_t)row * Nn + n0 + cw + l16;
#pragma unroll
        for (int ni = 0; ni < 4; ni++) {
          float v = acc[mi][ni][r] + bv[ni];
          po[ni * 16] = f2b(0.5f * v * (1.0f + erff(v * 0.70710678f)));
        }
      }
    }
  }
}

// one block per (window p, head h). S=QK^T*scale, softmax rows, O=PV.
// qkv rows are already permuted; epilogue scatters rows back via order[].
__global__ __launch_bounds__(256, 2) void attn_kernel(
    const ushort* __restrict__ qkv, const int* __restrict__ order,
    ushort* __restrict__ out) {
  __shared__ ushort sQ[128 * 32];
  __shared__ ushort sK[128 * 32];
  __shared__ ushort sVt[32 * 136];   // V transposed [d][j], padded stride
  __shared__ ushort sP[128 * 136];   // probabilities, padded stride
  const int p = blockIdx.x >> 3;
  const int h = blockIdx.x & 7;
  const int tid = threadIdx.x;
  const int wave = tid >> 6, lane = tid & 63;
  const int quad = lane >> 4, l16 = lane & 15;
  const size_t rowbase = (size_t)(p * K_WIN) * 768;

  {  // stage Q, K (async, 16B chunks: 4 chunks per 32-col row)
    int a = tid, b = tid + 256;
    const ushort* gq0 = qkv + rowbase + (size_t)(a >> 2) * 768 + h * 32 + (a & 3) * 8;
    const ushort* gq1 = qkv + rowbase + (size_t)(b >> 2) * 768 + h * 32 + (b & 3) * 8;
    cp16(gq0, sQ + wave * 512);
    cp16(gq1, sQ + 2048 + wave * 512);
    cp16(gq0 + 256, sK + wave * 512);
    cp16(gq1 + 256, sK + 2048 + wave * 512);
  }
  {  // stage V transposed
    int r = tid >> 1, cb = (tid & 1) * 16;
    const ushort* gv = qkv + rowbase + (size_t)r * 768 + 512 + h * 32 + cb;
    __align__(16) ushort tmp[16];
    *(uint4*)(tmp) = *(const uint4*)(gv);
    *(uint4*)(tmp + 8) = *(const uint4*)(gv + 8);
#pragma unroll
    for (int i = 0; i < 16; i++) sVt[(cb + i) * 136 + r] = tmp[i];
  }
  __syncthreads();

  // QK^T: wave handles 32-row stripe across all 128 cols (2x8 frags)
  const int rw2 = wave * 32;
  f32x4 s[2][8] = {};
  bf16x8 qa[2];
#pragma unroll
  for (int mi = 0; mi < 2; mi++)
    qa[mi] = *(const bf16x8*)(sQ + (rw2 + mi * 16 + l16) * 32 + quad * 8);
#pragma unroll
  for (int nj = 0; nj < 8; nj++) {
    bf16x8 kb = *(const bf16x8*)(sK + (nj * 16 + l16) * 32 + quad * 8);
#pragma unroll
    for (int mi = 0; mi < 2; mi++)
      s[mi][nj] = __builtin_amdgcn_mfma_f32_16x16x32_bf16(qa[mi], kb, s[mi][nj], 0, 0, 0);
  }

  // row softmax fully in registers (row = 8 regs x 16 lanes of same quad)
#pragma unroll
  for (int mi = 0; mi < 2; mi++) {
#pragma unroll
    for (int r = 0; r < 4; r++) {
      float t[8];
      float mx = -1e30f;
#pragma unroll
      for (int nj = 0; nj < 8; nj++) {
        t[nj] = s[mi][nj][r] * ATTN_SCALE;
        mx = fmaxf(mx, t[nj]);
      }
#pragma unroll
      for (int off = 1; off < 16; off <<= 1) mx = fmaxf(mx, __shfl_xor(mx, off));
      float sm = 0.0f;
#pragma unroll
      for (int nj = 0; nj < 8; nj++) {
        t[nj] = __expf(t[nj] - mx);
        sm += t[nj];
      }
#pragma unroll
      for (int off = 1; off < 16; off <<= 1) sm += __shfl_xor(sm, off);
      float inv = 1.0f / sm;
      int prow = rw2 + mi * 16 + quad * 4 + r;
#pragma unroll
      for (int nj = 0; nj < 8; nj++)
        sP[prow * 136 + nj * 16 + l16] = f2b(t[nj] * inv);
    }
  }
  __syncthreads();

  // O = P @ V : M=32-row stripe, N=32 (2 tiles), K=128 (4 steps)
  f32x4 o[2][2] = {};
#pragma unroll
  for (int kk = 0; kk < 4; kk++) {
    bf16x8 pa[2], vb[2];
#pragma unroll
    for (int mi = 0; mi < 2; mi++)
      pa[mi] = *(const bf16x8*)(sP + (rw2 + mi * 16 + l16) * 136 + kk * 32 + quad * 8);
#pragma unroll
    for (int ni = 0; ni < 2; ni++)
      vb[ni] = *(const bf16x8*)(sVt + (ni * 16 + l16) * 136 + kk * 32 + quad * 8);
#pragma unroll
    for (int mi = 0; mi < 2; mi++)
#pragma unroll
      for (int ni = 0; ni < 2; ni++)
        o[mi][ni] = __builtin_amdgcn_mfma_f32_16x16x32_bf16(pa[mi], vb[ni], o[mi][ni], 0, 0, 0);
  }

#pragma unroll
  for (int mi = 0; mi < 2; mi++) {
#pragma unroll
    for (int r = 0; r < 4; r++) {
      int row = rw2 + mi * 16 + quad * 4 + r;
      int g = order[p * K_WIN + row];
      ushort* po = out + (size_t)g * C_DIM + h * 32 + l16;
      po[0] = f2b(o[mi][0][r]);
      po[16] = f2b(o[mi][1][r]);
    }
  }
}

extern "C" void kernel_launch(void* const* d_in, const int* in_sizes, int n_in,
                              void* d_out, int out_size, void* d_ws, size_t ws_size,
                              hipStream_t stream) {
  const float* feat = (const float*)d_in[0];
  const int* order = (const int*)d_in[1];
  const int* inverse = (const int*)d_in[2];
  const float* qkv_w = (const float*)d_in[3];
  const float* qkv_b = (const float*)d_in[4];
  const float* proj_w = (const float*)d_in[5];
  const float* proj_b = (const float*)d_in[6];
  const float* ln1_g = (const float*)d_in[7];
  const float* ln1_b = (const float*)d_in[8];
  const float* ln2_g = (const float*)d_in[9];
  const float* ln2_b = (const float*)d_in[10];
  const float* mlp_w1 = (const float*)d_in[11];
  const float* mlp_b1 = (const float*)d_in[12];
  const float* mlp_w2 = (const float*)d_in[13];
  const float* mlp_b2 = (const float*)d_in[14];
  float* out = (float*)d_out;

  char* ws = (char*)d_ws;
  ushort* xln = (ushort*)(ws);                                   // 64 MiB (reused as y_ln)
  ushort* qkvp = (ushort*)(ws + 67108864);                       // 192 MiB
  ushort* attn = (ushort*)(ws + 67108864 + 201326592);           // 64 MiB
  ushort* hbuf = qkvp;                                           // 256 MiB overlay (qkv+attn dead)
  ushort* wq = (ushort*)(ws + 335544320);
  ushort* wp = wq + 196608;
  ushort* w1 = wp + 65536;
  ushort* w2 = w1 + 262144;

  f2b_kernel<<<768, 256, 0, stream>>>(qkv_w, wq, 196608);
  f2b_kernel<<<256, 256, 0, stream>>>(proj_w, wp, 65536);
  f2b_kernel<<<1024, 256, 0, stream>>>(mlp_w1, w1, 262144);
  f2b_kernel<<<1024, 256, 0, stream>>>(mlp_w2, w2, 262144);

  ln_kernel<<<N_TOK / 4, 256, 0, stream>>>(feat, ln1_g, ln1_b, xln);
  // QKV, scattered into permuted order via inverse[]
  gemm_bt<0><<<(N_TOK / 128) * 6, 256, 0, stream>>>(xln, wq, qkv_b, qkvp, inverse, nullptr,
                                                    N_TOK, 768, 256);
  attn_kernel<<<NB * H_HEADS, 256, 0, stream>>>(qkvp, order, attn);
  // x = feat + attn @ proj_w^T + proj_b  -> d_out (fp32 scratch for residual)
  gemm_bt<1><<<(N_TOK / 128) * 2, 256, 0, stream>>>(attn, wp, proj_b, out, nullptr, feat,
                                                    N_TOK, 256, 256);
  ln_kernel<<<N_TOK / 4, 256, 0, stream>>>(out, ln2_g, ln2_b, xln);
  // h = gelu(y_ln @ w1^T + b1)
  gemm_bt<2><<<(N_TOK / 128) * 8, 256, 0, stream>>>(xln, w1, mlp_b1, hbuf, nullptr, nullptr,
                                                    N_TOK, 1024, 256);
  // out = x + h @ w2^T + b2  (self-aliased read-then-write per element: safe)
  gemm_bt<1><<<(N_TOK / 128) * 2, 256, 0, stream>>>(hbuf, w2, mlp_b2, out, nullptr, out,
                                                    N_TOK, 256, 1024);
}

// Round 2
// 826.325 us; speedup vs baseline: 1.0506x; 1.0506x over previous
//
#include <hip/hip_runtime.h>

typedef unsigned short ushort;
typedef float f32x4 __attribute__((ext_vector_type(4)));
typedef __bf16 bf16x8 __attribute__((ext_vector_type(8)));

#define N_TOK 131072
#define C_DIM 256
#define H_HEADS 8
#define K_WIN 128
#define NB (N_TOK / K_WIN)
#define ATTN_SCALE 0.17677669529663687f
#define LN_EPS 1e-5f

__device__ __forceinline__ ushort f2b(float f) {
  unsigned u = __float_as_uint(f);
  unsigned r = (u + 0x7fffu + ((u >> 16) & 1u)) >> 16;
  return (ushort)r;
}

// async global->LDS 16B copy. LDS dest is wave-uniform base + lane*16;
// global source may be a per-lane address.
__device__ __forceinline__ void cp16(const void* gptr, void* lptr) {
  __builtin_amdgcn_global_load_lds(
      (const __attribute__((address_space(1))) unsigned int*)(unsigned long long)gptr,
      (__attribute__((address_space(3))) unsigned int*)(unsigned)(unsigned long long)lptr,
      16, 0, 0);
}

__global__ void f2b_kernel(const float* __restrict__ in, ushort* __restrict__ out, int n) {
  int i = blockIdx.x * 256 + threadIdx.x;
  if (i < n) out[i] = f2b(in[i]);
}

// LayerNorm over 256 cols, one wave per row, fp32 in -> bf16 out
__global__ __launch_bounds__(256) void ln_kernel(const float* __restrict__ x,
                                                 const float* __restrict__ g,
                                                 const float* __restrict__ b,
                                                 ushort* __restrict__ out) {
  int row = blockIdx.x * 4 + (threadIdx.x >> 6);
  int lane = threadIdx.x & 63;
  const float4* px = reinterpret_cast<const float4*>(x + (size_t)row * C_DIM);
  float4 v = px[lane];
  float s = v.x + v.y + v.z + v.w;
#pragma unroll
  for (int off = 32; off; off >>= 1) s += __shfl_xor(s, off);
  float mu = s * (1.0f / C_DIM);
  float dx = v.x - mu, dy = v.y - mu, dz = v.z - mu, dw = v.w - mu;
  float q = dx * dx + dy * dy + dz * dz + dw * dw;
#pragma unroll
  for (int off = 32; off; off >>= 1) q += __shfl_xor(q, off);
  float rstd = rsqrtf(q * (1.0f / C_DIM) + LN_EPS);
  float4 gv = reinterpret_cast<const float4*>(g)[lane];
  float4 bv = reinterpret_cast<const float4*>(b)[lane];
  ushort4 o;
  o.x = f2b(dx * rstd * gv.x + bv.x);
  o.y = f2b(dy * rstd * gv.y + bv.y);
  o.z = f2b(dz * rstd * gv.z + bv.z);
  o.w = f2b(dw * rstd * gv.w + bv.w);
  reinterpret_cast<ushort4*>(out + (size_t)row * C_DIM)[lane] = o;
}

// C = A(MxK) @ B(NxK)^T, bf16 in. 128x128 tile, BK=64, XOR-swizzled LDS,
// XCD-aware block mapping (xcd = bid&7 owns an M-slab, nt-inner for L2 reuse).
// EPI 0: bf16 out = acc + bias                      [QKV]
// EPI 1: f32 out  = acc + bias + resid              [proj / mlp2]
// EPI 2: bf16 out = gelu_exact(acc + bias)          [mlp1]
template <int EPI>
__global__ __launch_bounds__(256, 2) void gemm_bt(
    const ushort* __restrict__ A, const ushort* __restrict__ B,
    const float* __restrict__ bias, void* __restrict__ out,
    const float* __restrict__ resid, int M, int Nn, int Kk) {
  __shared__ ushort sA[128 * 64];
  __shared__ ushort sB[128 * 64];
  const int tid = threadIdx.x;
  const int wave = tid >> 6;
  const int lane = tid & 63;
  const int quad = lane >> 4;
  const int l16 = lane & 15;
  const int ntn = Nn >> 7;
  const int nmt = M >> 7;
  // XCD-aware: assumes round-robin bid->XCD. XCD x owns M-slab, iterates nt inner.
  const int x = blockIdx.x & 7;
  const int i = blockIdx.x >> 3;
  const int mt = x * (nmt >> 3) + i / ntn;
  const int nt = i % ntn;
  const int m0 = mt << 7, n0 = nt << 7;
  const int rw = (wave >> 1) << 6;
  const int cw = (wave & 1) << 6;
  // staging: each cp16 covers 8 rows x 128B; lane -> row r0+(l>>3), swizzled chunk
  const int lrow = lane >> 3;
  const int sch = ((lane & 7) ^ lrow) << 3;  // element offset within 64-col row

  f32x4 acc[4][4] = {};

  for (int k0 = 0; k0 < Kk; k0 += 64) {
    __syncthreads();  // protect LDS while prior reads in flight
#pragma unroll
    for (int j = 0; j < 4; j++) {
      int r = (wave << 5) + (j << 3) + lrow;
      cp16(A + ((size_t)(m0 + r) * Kk + k0 + sch), sA + (wave << 11) + (j << 9));
      cp16(B + ((size_t)(n0 + r) * Kk + k0 + sch), sB + (wave << 11) + (j << 9));
    }
    __syncthreads();  // staging complete

#pragma unroll
    for (int kk = 0; kk < 2; kk++) {
      bf16x8 af[4], bfr[4];
#pragma unroll
      for (int ii = 0; ii < 4; ii++) {
        int row = rw + ii * 16 + l16;
        af[ii] = *(const bf16x8*)(sA + row * 64 + ((((kk << 2) | quad) ^ (row & 7)) << 3));
      }
#pragma unroll
      for (int ii = 0; ii < 4; ii++) {
        int row = cw + ii * 16 + l16;
        bfr[ii] = *(const bf16x8*)(sB + row * 64 + ((((kk << 2) | quad) ^ (row & 7)) << 3));
      }
#pragma unroll
      for (int mi = 0; mi < 4; mi++)
#pragma unroll
        for (int ni = 0; ni < 4; ni++)
          acc[mi][ni] = __builtin_amdgcn_mfma_f32_16x16x32_bf16(af[mi], bfr[ni], acc[mi][ni], 0, 0, 0);
    }
  }

  float bv[4];
#pragma unroll
  for (int ni = 0; ni < 4; ni++) bv[ni] = bias[n0 + cw + ni * 16 + l16];

#pragma unroll
  for (int mi = 0; mi < 4; mi++) {
#pragma unroll
    for (int r = 0; r < 4; r++) {
      int row = m0 + rw + mi * 16 + quad * 4 + r;
      if (EPI == 0) {
        ushort* po = (ushort*)out + (size_t)row * Nn + n0 + cw + l16;
#pragma unroll
        for (int ni = 0; ni < 4; ni++) po[ni * 16] = f2b(acc[mi][ni][r] + bv[ni]);
      } else if (EPI == 1) {
        size_t base = (size_t)row * Nn + n0 + cw + l16;
        float* po = (float*)out;
#pragma unroll
        for (int ni = 0; ni < 4; ni++)
          po[base + ni * 16] = acc[mi][ni][r] + bv[ni] + resid[base + ni * 16];
      } else {
        ushort* po = (ushort*)out + (size_t)row * Nn + n0 + cw + l16;
#pragma unroll
        for (int ni = 0; ni < 4; ni++) {
          float v = acc[mi][ni][r] + bv[ni];
          po[ni * 16] = f2b(0.5f * v * (1.0f + erff(v * 0.70710678f)));
        }
      }
    }
  }
}

// one block per (window p, head h). qkv stored UNPERMUTED; rows gathered via
// order[] at staging. Window-grouped XCD swizzle: all 8 heads of a window run
// on the same XCD so gathered rows are fetched once into that XCD's L2.
__global__ __launch_bounds__(256, 2) void attn_kernel(
    const ushort* __restrict__ qkv, const int* __restrict__ order,
    ushort* __restrict__ out) {
  __shared__ ushort sQ[128 * 32];
  __shared__ ushort sK[128 * 32];
  __shared__ ushort sVt[32 * 136];   // V transposed [d][j], padded stride
  __shared__ ushort sP[128 * 136];   // probabilities, padded stride
  const int xcd = blockIdx.x & 7;
  const int bi = blockIdx.x >> 3;
  const int p = (bi >> 3) * 8 + xcd;   // window
  const int h = bi & 7;                // head
  const int tid = threadIdx.x;
  const int wave = tid >> 6, lane = tid & 63;
  const int quad = lane >> 4, l16 = lane & 15;

  {  // stage Q, K (gathered rows; 4 lanes x 16B per 64B row-segment)
    int a = tid, b = tid + 256;
    int ga = order[p * K_WIN + (a >> 2)];
    int gb = order[p * K_WIN + (b >> 2)];
    const ushort* gq0 = qkv + (size_t)ga * 768 + h * 32 + (a & 3) * 8;
    const ushort* gq1 = qkv + (size_t)gb * 768 + h * 32 + (b & 3) * 8;
    cp16(gq0, sQ + wave * 512);
    cp16(gq1, sQ + 2048 + wave * 512);
    cp16(gq0 + 256, sK + wave * 512);
    cp16(gq1 + 256, sK + 2048 + wave * 512);
  }
  {  // stage V transposed (gathered)
    int r = tid >> 1, cb = (tid & 1) * 16;
    int gr = order[p * K_WIN + r];
    const ushort* gv = qkv + (size_t)gr * 768 + 512 + h * 32 + cb;
    __align__(16) ushort tmp[16];
    *(uint4*)(tmp) = *(const uint4*)(gv);
    *(uint4*)(tmp + 8) = *(const uint4*)(gv + 8);
#pragma unroll
    for (int i = 0; i < 16; i++) sVt[(cb + i) * 136 + r] = tmp[i];
  }
  __syncthreads();

  // QK^T: wave handles 32-row stripe across all 128 cols (2x8 frags)
  const int rw2 = wave * 32;
  f32x4 s[2][8] = {};
  bf16x8 qa[2];
#pragma unroll
  for (int mi = 0; mi < 2; mi++)
    qa[mi] = *(const bf16x8*)(sQ + (rw2 + mi * 16 + l16) * 32 + quad * 8);
#pragma unroll
  for (int nj = 0; nj < 8; nj++) {
    bf16x8 kb = *(const bf16x8*)(sK + (nj * 16 + l16) * 32 + quad * 8);
#pragma unroll
    for (int mi = 0; mi < 2; mi++)
      s[mi][nj] = __builtin_amdgcn_mfma_f32_16x16x32_bf16(qa[mi], kb, s[mi][nj], 0, 0, 0);
  }

  // row softmax fully in registers (row = 8 regs x 16 lanes of same quad)
#pragma unroll
  for (int mi = 0; mi < 2; mi++) {
#pragma unroll
    for (int r = 0; r < 4; r++) {
      float t[8];
      float mx = -1e30f;
#pragma unroll
      for (int nj = 0; nj < 8; nj++) {
        t[nj] = s[mi][nj][r] * ATTN_SCALE;
        mx = fmaxf(mx, t[nj]);
      }
#pragma unroll
      for (int off = 1; off < 16; off <<= 1) mx = fmaxf(mx, __shfl_xor(mx, off));
      float sm = 0.0f;
#pragma unroll
      for (int nj = 0; nj < 8; nj++) {
        t[nj] = __expf(t[nj] - mx);
        sm += t[nj];
      }
#pragma unroll
      for (int off = 1; off < 16; off <<= 1) sm += __shfl_xor(sm, off);
      float inv = 1.0f / sm;
      int prow = rw2 + mi * 16 + quad * 4 + r;
#pragma unroll
      for (int nj = 0; nj < 8; nj++)
        sP[prow * 136 + nj * 16 + l16] = f2b(t[nj] * inv);
    }
  }
  __syncthreads();

  // O = P @ V : M=32-row stripe, N=32 (2 tiles), K=128 (4 steps)
  f32x4 o[2][2] = {};
#pragma unroll
  for (int kk = 0; kk < 4; kk++) {
    bf16x8 pa[2], vb[2];
#pragma unroll
    for (int mi = 0; mi < 2; mi++)
      pa[mi] = *(const bf16x8*)(sP + (rw2 + mi * 16 + l16) * 136 + kk * 32 + quad * 8);
#pragma unroll
    for (int ni = 0; ni < 2; ni++)
      vb[ni] = *(const bf16x8*)(sVt + (ni * 16 + l16) * 136 + kk * 32 + quad * 8);
#pragma unroll
    for (int mi = 0; mi < 2; mi++)
#pragma unroll
      for (int ni = 0; ni < 2; ni++)
        o[mi][ni] = __builtin_amdgcn_mfma_f32_16x16x32_bf16(pa[mi], vb[ni], o[mi][ni], 0, 0, 0);
  }

  // scatter rows back to original token order (same-window heads share rows
  // -> same-XCD L2 write locality)
#pragma unroll
  for (int mi = 0; mi < 2; mi++) {
#pragma unroll
    for (int r = 0; r < 4; r++) {
      int row = rw2 + mi * 16 + quad * 4 + r;
      int g = order[p * K_WIN + row];
      ushort* po = out + (size_t)g * C_DIM + h * 32 + l16;
      po[0] = f2b(o[mi][0][r]);
      po[16] = f2b(o[mi][1][r]);
    }
  }
}

extern "C" void kernel_launch(void* const* d_in, const int* in_sizes, int n_in,
                              void* d_out, int out_size, void* d_ws, size_t ws_size,
                              hipStream_t stream) {
  const float* feat = (const float*)d_in[0];
  const int* order = (const int*)d_in[1];
  const float* qkv_w = (const float*)d_in[3];
  const float* qkv_b = (const float*)d_in[4];
  const float* proj_w = (const float*)d_in[5];
  const float* proj_b = (const float*)d_in[6];
  const float* ln1_g = (const float*)d_in[7];
  const float* ln1_b = (const float*)d_in[8];
  const float* ln2_g = (const float*)d_in[9];
  const float* ln2_b = (const float*)d_in[10];
  const float* mlp_w1 = (const float*)d_in[11];
  const float* mlp_b1 = (const float*)d_in[12];
  const float* mlp_w2 = (const float*)d_in[13];
  const float* mlp_b2 = (const float*)d_in[14];
  float* out = (float*)d_out;

  char* ws = (char*)d_ws;
  ushort* xln = (ushort*)(ws);                                   // 64 MiB (reused as y_ln)
  ushort* qkvp = (ushort*)(ws + 67108864);                       // 192 MiB (unpermuted now)
  ushort* attn = (ushort*)(ws + 67108864 + 201326592);           // 64 MiB
  ushort* hbuf = qkvp;                                           // 256 MiB overlay (qkv+attn dead)
  ushort* wq = (ushort*)(ws + 335544320);
  ushort* wp = wq + 196608;
  ushort* w1 = wp + 65536;
  ushort* w2 = w1 + 262144;

  f2b_kernel<<<768, 256, 0, stream>>>(qkv_w, wq, 196608);
  f2b_kernel<<<256, 256, 0, stream>>>(proj_w, wp, 65536);
  f2b_kernel<<<1024, 256, 0, stream>>>(mlp_w1, w1, 262144);
  f2b_kernel<<<1024, 256, 0, stream>>>(mlp_w2, w2, 262144);

  ln_kernel<<<N_TOK / 4, 256, 0, stream>>>(feat, ln1_g, ln1_b, xln);
  // QKV (unpermuted, coalesced writes)
  gemm_bt<0><<<(N_TOK / 128) * 6, 256, 0, stream>>>(xln, wq, qkv_b, qkvp, nullptr,
                                                    N_TOK, 768, 256);
  attn_kernel<<<NB * H_HEADS, 256, 0, stream>>>(qkvp, order, attn);
  // x = feat + attn @ proj_w^T + proj_b  -> d_out (fp32 scratch for residual)
  gemm_bt<1><<<(N_TOK / 128) * 2, 256, 0, stream>>>(attn, wp, proj_b, out, feat,
                                                    N_TOK, 256, 256);
  ln_kernel<<<N_TOK / 4, 256, 0, stream>>>(out, ln2_g, ln2_b, xln);
  // h = gelu(y_ln @ w1^T + b1)
  gemm_bt<2><<<(N_TOK / 128) * 8, 256, 0, stream>>>(xln, w1, mlp_b1, hbuf, nullptr,
                                                    N_TOK, 1024, 256);
  // out = x + h @ w2^T + b2  (self-aliased read-then-write per element: safe)
  gemm_bt<1><<<(N_TOK / 128) * 2, 256, 0, stream>>>(hbuf, w2, mlp_b2, out, out,
                                                    N_TOK, 256, 1024);
}